// Round 2
// baseline (119.081 us; speedup 1.0000x reference)
//
#include <hip/hip_runtime.h>

typedef float f32x4 __attribute__((ext_vector_type(4)));
typedef __bf16 bf16x8 __attribute__((ext_vector_type(8)));
typedef __bf16 bf16x4 __attribute__((ext_vector_type(4)));

#define B_ 8
#define T_ 2048
#define DE 1024
#define DQ 64
#define SCALE 0.125f
#define XS_LD 1032   // 1024 + 8 pad: row stride 2064B -> 2-way banks on b128 (free)

// ---------- kernel 0: Wt[n][k] = W[k][n] as bf16, n in [0,192), k in [0,1024)
__global__ __launch_bounds__(256) void kw_transpose(
    const float* __restrict__ Wq, const float* __restrict__ Wk,
    const float* __restrict__ Wv, __bf16* __restrict__ Wt)
{
  int idx = blockIdx.x * 256 + threadIdx.x;     // 0 .. 196607
  int n = idx >> 10, k = idx & 1023;
  const float* W = (n < 64) ? Wq : ((n < 128) ? Wk : Wv);
  Wt[idx] = (__bf16)W[k * 64 + (n & 63)];
}

// ---------- kernel 1: QKV projection, 1 block = 16-row m-tile, 4 waves x 3 n-tiles
__global__ __launch_bounds__(256) void kproj(
    const float* __restrict__ x, const __bf16* __restrict__ Wt,
    __bf16* __restrict__ Qb, __bf16* __restrict__ Kb, __bf16* __restrict__ Vt)
{
  __shared__ __bf16 xs[16 * XS_LD];             // 33 KB -> 4 blocks/CU, 16 waves/CU
  const int tid = threadIdx.x;
  const int lane = tid & 63;
  const int widx = tid >> 6;
  const int col = lane & 15, g = lane >> 4;
  const int mbase = blockIdx.x * 16;

  // stage 16x1024 of x -> bf16 LDS (coalesced 32B/lane, writes conflict-free)
#pragma unroll
  for (int i = 0; i < 8; ++i) {
    int e = (i * 256 + tid) * 8;
    int row = e >> 10, kp = e & 1023;
    const float* src = x + (size_t)(mbase + row) * DE + kp;
    f32x4 a0 = *(const f32x4*)(src);
    f32x4 a1 = *(const f32x4*)(src + 4);
    bf16x8 v;
#pragma unroll
    for (int j = 0; j < 4; ++j) { v[j] = (__bf16)a0[j]; v[4 + j] = (__bf16)a1[j]; }
    *(bf16x8*)&xs[row * XS_LD + kp] = v;
  }
  __syncthreads();

  const int t0 = widx * 3;                      // this wave's 3 n-tiles
  f32x4 acc[3];
#pragma unroll
  for (int i = 0; i < 3; ++i) acc[i] = (f32x4){0.f, 0.f, 0.f, 0.f};

  const __bf16* Wp = Wt + (size_t)(t0 * 16 + col) * DE + g * 8;
#pragma unroll 4
  for (int kk = 0; kk < DE; kk += 32) {
    bf16x8 af = *(const bf16x8*)&xs[col * XS_LD + kk + g * 8];
    bf16x8 b0 = *(const bf16x8*)(Wp + kk);
    bf16x8 b1 = *(const bf16x8*)(Wp + 16 * DE + kk);
    bf16x8 b2 = *(const bf16x8*)(Wp + 32 * DE + kk);
    acc[0] = __builtin_amdgcn_mfma_f32_16x16x32_bf16(af, b0, acc[0], 0, 0, 0);
    acc[1] = __builtin_amdgcn_mfma_f32_16x16x32_bf16(af, b1, acc[1], 0, 0, 0);
    acc[2] = __builtin_amdgcn_mfma_f32_16x16x32_bf16(af, b2, acc[2], 0, 0, 0);
  }

  // epilogue: D layout row = g*4+r, col = ti*16 + (lane&15)
  const int b = mbase >> 11;
  const int trow = mbase & 2047;
#pragma unroll
  for (int ii = 0; ii < 3; ++ii) {
    int ti = t0 + ii;
    if (ti < 8) {
      __bf16* dst = (ti < 4) ? Qb : Kb;
      int c = (ti & 3) * 16 + col;
#pragma unroll
      for (int r = 0; r < 4; ++r)
        dst[(size_t)(mbase + g * 4 + r) * DQ + c] = (__bf16)acc[ii][r];
    } else {
      int d = (ti - 8) * 16 + col;
      bf16x4 v;
#pragma unroll
      for (int r = 0; r < 4; ++r) v[r] = (__bf16)acc[ii][r];
      *(bf16x4*)(Vt + ((size_t)(b * DQ + d)) * T_ + trow + g * 4) = v;
    }
  }
}

// ---------- kernel 2: causal flash attention, block = 1 q-tile, KV split over 4 waves
__global__ __launch_bounds__(256) void kattn(
    const __bf16* __restrict__ Qb, const __bf16* __restrict__ Kb,
    const __bf16* __restrict__ Vt, float* __restrict__ out)
{
  __shared__ float accs[4][16][68];             // [wave][row][col], 68-pad -> 2-way banks
  __shared__ float mls[4][2][16];               // [wave][m/l][row]
  __shared__ __bf16 plds[4][16][40];            // P D->A transpose, wave-private

  const int tid = threadIdx.x;
  const int lane = tid & 63;
  const int w = tid >> 6;
  const int col = lane & 15, g = lane >> 4;
  const int b = blockIdx.x >> 7;
  const int jq = 127 - (blockIdx.x & 127);      // long q-tiles dispatched first
  const int qbase = jq * 16;

  const __bf16* Qp = Qb + (size_t)(b * T_ + qbase + col) * DQ + g * 8;
  bf16x8 q0 = *(const bf16x8*)(Qp);
  bf16x8 q1 = *(const bf16x8*)(Qp + 32);

  const __bf16* Kbb = Kb + (size_t)b * T_ * DQ;
  const __bf16* Vbb = Vt + (size_t)b * DQ * T_;

  f32x4 acc0 = {0.f,0.f,0.f,0.f}, acc1 = {0.f,0.f,0.f,0.f};
  f32x4 acc2 = {0.f,0.f,0.f,0.f}, acc3 = {0.f,0.f,0.f,0.f};
  float mrun[4], lsum[4];
#pragma unroll
  for (int r = 0; r < 4; ++r) { mrun[r] = -1e30f; lsum[r] = 0.f; }

  const int nb = (jq >> 1) + 1;                 // KV blocks of 32 for this q-tile
  for (int it = w; it < nb; it += 4) {          // round-robin KV split across waves
    const int nbase = it * 32;
    const __bf16* Kp = Kbb + (size_t)(nbase + col) * DQ + g * 8;
    bf16x8 k00 = *(const bf16x8*)(Kp);
    bf16x8 k01 = *(const bf16x8*)(Kp + 32);
    bf16x8 k10 = *(const bf16x8*)(Kp + 16 * DQ);
    bf16x8 k11 = *(const bf16x8*)(Kp + 16 * DQ + 32);

    f32x4 s0 = {0.f,0.f,0.f,0.f}, s1 = {0.f,0.f,0.f,0.f};
    s0 = __builtin_amdgcn_mfma_f32_16x16x32_bf16(q0, k00, s0, 0, 0, 0);
    s0 = __builtin_amdgcn_mfma_f32_16x16x32_bf16(q1, k01, s0, 0, 0, 0);
    s1 = __builtin_amdgcn_mfma_f32_16x16x32_bf16(q0, k10, s1, 0, 0, 0);
    s1 = __builtin_amdgcn_mfma_f32_16x16x32_bf16(q1, k11, s1, 0, 0, 0);

    float p0[4], p1[4];
#pragma unroll
    for (int r = 0; r < 4; ++r) { p0[r] = s0[r] * SCALE; p1[r] = s1[r] * SCALE; }

    if (it == nb - 1) {                          // only last block touches the diagonal
#pragma unroll
      for (int r = 0; r < 4; ++r) {
        int m = qbase + g * 4 + r;
        if (nbase + col > m)      p0[r] = -1e30f;
        if (nbase + 16 + col > m) p1[r] = -1e30f;
      }
    }

    float mv[4];
#pragma unroll
    for (int r = 0; r < 4; ++r) mv[r] = fmaxf(p0[r], p1[r]);
#pragma unroll
    for (int sh = 1; sh <= 8; sh <<= 1) {
#pragma unroll
      for (int r = 0; r < 4; ++r) mv[r] = fmaxf(mv[r], __shfl_xor(mv[r], sh, 64));
    }

    float rs[4];
#pragma unroll
    for (int r = 0; r < 4; ++r) {
      float mn = fmaxf(mrun[r], mv[r]);
      rs[r] = __expf(mrun[r] - mn);
      mrun[r] = mn;
      p0[r] = __expf(p0[r] - mn);
      p1[r] = __expf(p1[r] - mn);
      lsum[r] = lsum[r] * rs[r] + p0[r] + p1[r];
    }
#pragma unroll
    for (int r = 0; r < 4; ++r) {
      acc0[r] *= rs[r]; acc1[r] *= rs[r]; acc2[r] *= rs[r]; acc3[r] *= rs[r];
      plds[w][g * 4 + r][col]      = (__bf16)p0[r];
      plds[w][g * 4 + r][16 + col] = (__bf16)p1[r];
    }

    bf16x8 pf = *(const bf16x8*)&plds[w][col][g * 8];   // D->A layout, wave-private

    const __bf16* Vp = Vbb + (size_t)col * T_ + nbase + g * 8;
    bf16x8 v0 = *(const bf16x8*)(Vp);
    bf16x8 v1 = *(const bf16x8*)(Vp + 16 * T_);
    bf16x8 v2 = *(const bf16x8*)(Vp + 32 * T_);
    bf16x8 v3 = *(const bf16x8*)(Vp + 48 * T_);

    acc0 = __builtin_amdgcn_mfma_f32_16x16x32_bf16(pf, v0, acc0, 0, 0, 0);
    acc1 = __builtin_amdgcn_mfma_f32_16x16x32_bf16(pf, v1, acc1, 0, 0, 0);
    acc2 = __builtin_amdgcn_mfma_f32_16x16x32_bf16(pf, v2, acc2, 0, 0, 0);
    acc3 = __builtin_amdgcn_mfma_f32_16x16x32_bf16(pf, v3, acc3, 0, 0, 0);
  }

  // per-wave: full row-sum over the 16 col lanes
#pragma unroll
  for (int sh = 1; sh <= 8; sh <<= 1) {
#pragma unroll
    for (int r = 0; r < 4; ++r) lsum[r] += __shfl_xor(lsum[r], sh, 64);
  }

  // publish per-wave partial state
#pragma unroll
  for (int r = 0; r < 4; ++r) {
    int row = g * 4 + r;
    accs[w][row][col]      = acc0[r];
    accs[w][row][col + 16] = acc1[r];
    accs[w][row][col + 32] = acc2[r];
    accs[w][row][col + 48] = acc3[r];
    if (col == 0) { mls[w][0][row] = mrun[r]; mls[w][1][row] = lsum[r]; }
  }
  __syncthreads();

  // combine: lane (w,g,col) -> row = w*4+g, cols 4*col..4*col+3 (coalesced f32x4 out)
  {
    int row = w * 4 + g;
    int c4 = col * 4;
    float m0 = mls[0][0][row], m1 = mls[1][0][row];
    float m2 = mls[2][0][row], m3 = mls[3][0][row];
    float M = fmaxf(fmaxf(m0, m1), fmaxf(m2, m3));
    float s0 = __expf(m0 - M), s1 = __expf(m1 - M);
    float s2 = __expf(m2 - M), s3 = __expf(m3 - M);
    float L = s0 * mls[0][1][row] + s1 * mls[1][1][row]
            + s2 * mls[2][1][row] + s3 * mls[3][1][row];
    f32x4 a0 = *(const f32x4*)&accs[0][row][c4];
    f32x4 a1 = *(const f32x4*)&accs[1][row][c4];
    f32x4 a2 = *(const f32x4*)&accs[2][row][c4];
    f32x4 a3 = *(const f32x4*)&accs[3][row][c4];
    float inv = 1.f / L;
    f32x4 o;
#pragma unroll
    for (int j = 0; j < 4; ++j)
      o[j] = (s0 * a0[j] + s1 * a1[j] + s2 * a2[j] + s3 * a3[j]) * inv;
    *(f32x4*)(out + (size_t)(b * T_ + qbase + row) * DQ + c4) = o;
  }
}

extern "C" void kernel_launch(void* const* d_in, const int* in_sizes, int n_in,
                              void* d_out, int out_size, void* d_ws, size_t ws_size,
                              hipStream_t stream)
{
  const float* x  = (const float*)d_in[0];
  const float* Wq = (const float*)d_in[1];
  const float* Wk = (const float*)d_in[2];
  const float* Wv = (const float*)d_in[3];
  float* out = (float*)d_out;

  char* ws = (char*)d_ws;
  __bf16* Wt = (__bf16*)(ws);                                   // 384 KiB
  __bf16* Qb = (__bf16*)(ws + 0x80000);                         // 2 MiB
  __bf16* Kb = (__bf16*)(ws + 0x80000 + 0x200000);              // 2 MiB
  __bf16* Vt = (__bf16*)(ws + 0x80000 + 0x400000);              // 2 MiB

  kw_transpose<<<768, 256, 0, stream>>>(Wq, Wk, Wv, Wt);
  kproj<<<1024, 256, 0, stream>>>(x, Wt, Qb, Kb, Vt);
  kattn<<<1024, 256, 0, stream>>>(Qb, Kb, Vt, out);
}

// Round 3
// 88.073 us; speedup vs baseline: 1.3521x; 1.3521x over previous
//
#include <hip/hip_runtime.h>

typedef float f32x4 __attribute__((ext_vector_type(4)));
typedef __bf16 bf16x8 __attribute__((ext_vector_type(8)));
typedef __bf16 bf16x4 __attribute__((ext_vector_type(4)));

#define B_ 8
#define T_ 2048
#define DE 1024
#define DQ 64
#define SCALE 0.125f
#define XS_LD 1032   // 1024 + 8 pad (bf16): row stride 2064B

// ---------- kernel 0: Wt[n][k] = W[k][n] as bf16 (coalesced READS, scattered writes)
__global__ __launch_bounds__(256) void kw_transpose(
    const float* __restrict__ Wq, const float* __restrict__ Wk,
    const float* __restrict__ Wv, __bf16* __restrict__ Wt)
{
  int idx = blockIdx.x * 256 + threadIdx.x;     // 0 .. 196607
  int m = idx >> 16;                            // which W
  int rem = idx & 65535;
  int k = rem >> 6, n = rem & 63;               // consecutive threads -> consecutive n: coalesced read
  const float* W = (m == 0) ? Wq : ((m == 1) ? Wk : Wv);
  Wt[((size_t)(m * 64 + n) << 10) | k] = (__bf16)W[k * 64 + n];
}

// ---------- kernel 1: QKV projection. Block = 32 m-rows, 4 waves: (msub, 6 n-tiles) each.
__global__ __launch_bounds__(256) void kproj(
    const float* __restrict__ x, const __bf16* __restrict__ Wt,
    __bf16* __restrict__ Qb, __bf16* __restrict__ Kb, __bf16* __restrict__ Vt)
{
  __shared__ __bf16 xs[32 * XS_LD];             // 66 KB -> 2 blocks/CU
  const int tid = threadIdx.x;
  const int lane = tid & 63;
  const int w = tid >> 6;
  const int col = lane & 15, g = lane >> 4;
  const int mbase = blockIdx.x * 32;

  // stage 32x1024 of x -> bf16 LDS (32B/lane/iter, coalesced)
#pragma unroll
  for (int i = 0; i < 16; ++i) {
    int e = (i * 256 + tid) * 8;
    int row = e >> 10, kp = e & 1023;
    const float* src = x + (size_t)(mbase + row) * DE + kp;
    f32x4 a0 = *(const f32x4*)(src);
    f32x4 a1 = *(const f32x4*)(src + 4);
    bf16x8 v;
#pragma unroll
    for (int j = 0; j < 4; ++j) { v[j] = (__bf16)a0[j]; v[4 + j] = (__bf16)a1[j]; }
    *(bf16x8*)&xs[row * XS_LD + kp] = v;
  }
  __syncthreads();

  const int msub = w & 1;                       // which 16-row half
  const int nt0 = (w >> 1) * 6;                 // 6 n-tiles per wave
  f32x4 acc[6];
#pragma unroll
  for (int i = 0; i < 6; ++i) acc[i] = (f32x4){0.f, 0.f, 0.f, 0.f};

  const __bf16* Wp = Wt + (size_t)(nt0 * 16 + col) * DE + g * 8;
  const __bf16* xr = &xs[(msub * 16 + col) * XS_LD + g * 8];
#pragma unroll 2
  for (int kk = 0; kk < DE; kk += 32) {
    bf16x8 af = *(const bf16x8*)(xr + kk);
#pragma unroll
    for (int ii = 0; ii < 6; ++ii) {
      bf16x8 bf = *(const bf16x8*)(Wp + (size_t)ii * 16 * DE + kk);
      acc[ii] = __builtin_amdgcn_mfma_f32_16x16x32_bf16(af, bf, acc[ii], 0, 0, 0);
    }
  }

  // epilogue: D layout row = g*4+r (within 16-row tile), col = ti*16 + col
  const int b = mbase >> 11;
  const int trow = (mbase & 2047) + msub * 16 + g * 4;
  const int mrow = mbase + msub * 16 + g * 4;
#pragma unroll
  for (int ii = 0; ii < 6; ++ii) {
    int ti = nt0 + ii;
    if (ti < 8) {
      __bf16* dst = (ti < 4) ? Qb : Kb;
      int c = (ti & 3) * 16 + col;
#pragma unroll
      for (int r = 0; r < 4; ++r)
        dst[(size_t)(mrow + r) * DQ + c] = (__bf16)acc[ii][r];
    } else {
      int d = (ti - 8) * 16 + col;
      bf16x4 v;
#pragma unroll
      for (int r = 0; r < 4; ++r) v[r] = (__bf16)acc[ii][r];
      *(bf16x4*)(Vt + ((size_t)(b * DQ + d)) * T_ + trow) = v;
    }
  }
}

// ---------- kernel 2: causal flash attention. Block = 32 q-rows, 4 waves split KV (KVB=64).
__global__ __launch_bounds__(256) void kattn(
    const __bf16* __restrict__ Qb, const __bf16* __restrict__ Kb,
    const __bf16* __restrict__ Vt, float* __restrict__ out)
{
  __shared__ float accs[4][32][68];             // 34.8 KB
  __shared__ float mls[4][2][32];               // 1 KB
  __shared__ __bf16 plds[4][2][16][72];         // 18.4 KB  (wave-private P transpose)

  const int tid = threadIdx.x;
  const int lane = tid & 63;
  const int w = tid >> 6;
  const int col = lane & 15, g = lane >> 4;
  const int b = blockIdx.x & 7;                 // batches interleaved: heavy q-tiles first
  const int jq = 63 - (blockIdx.x >> 3);
  const int qbase = jq * 32;

  // Q fragments for two 16-row m-tiles, held in registers
  bf16x8 qa[2][2];
#pragma unroll
  for (int mt = 0; mt < 2; ++mt) {
    const __bf16* Qp = Qb + (size_t)(b * T_ + qbase + mt * 16 + col) * DQ + g * 8;
    qa[mt][0] = *(const bf16x8*)(Qp);
    qa[mt][1] = *(const bf16x8*)(Qp + 32);
  }

  const __bf16* Kbb = Kb + (size_t)b * T_ * DQ;
  const __bf16* Vbb = Vt + (size_t)b * DQ * T_;

  f32x4 acc[2][4];
#pragma unroll
  for (int mt = 0; mt < 2; ++mt)
#pragma unroll
    for (int dt = 0; dt < 4; ++dt) acc[mt][dt] = (f32x4){0.f,0.f,0.f,0.f};
  float mrun[2][4], lsum[2][4];
#pragma unroll
  for (int mt = 0; mt < 2; ++mt)
#pragma unroll
    for (int r = 0; r < 4; ++r) { mrun[mt][r] = -1e30f; lsum[mt][r] = 0.f; }

  const int nb = (jq >> 1) + 1;                 // 64-key blocks covering [0, qbase+32)
  for (int it = w; it < nb; it += 4) {
    const int nbase = it * 64;

    // K fragments: 4 n-tiles x 2 k-frags
    bf16x8 kf_[4][2];
#pragma unroll
    for (int nt = 0; nt < 4; ++nt) {
      const __bf16* Kp = Kbb + (size_t)(nbase + nt * 16 + col) * DQ + g * 8;
      kf_[nt][0] = *(const bf16x8*)(Kp);
      kf_[nt][1] = *(const bf16x8*)(Kp + 32);
    }

    // QK^T: 16 MFMAs -> s[mt][nt], D layout row=g*4+r, col=key nt*16+col
    f32x4 s[2][4];
#pragma unroll
    for (int mt = 0; mt < 2; ++mt)
#pragma unroll
      for (int nt = 0; nt < 4; ++nt) {
        f32x4 t = __builtin_amdgcn_mfma_f32_16x16x32_bf16(qa[mt][0], kf_[nt][0],
                                                          (f32x4){0.f,0.f,0.f,0.f}, 0, 0, 0);
        s[mt][nt] = __builtin_amdgcn_mfma_f32_16x16x32_bf16(qa[mt][1], kf_[nt][1], t, 0, 0, 0);
      }

    // V fragments issued early (independent of softmax) to hide L2 latency
    bf16x8 vf[4][2];
#pragma unroll
    for (int dt = 0; dt < 4; ++dt) {
      const __bf16* Vp = Vbb + (size_t)(dt * 16 + col) * T_ + nbase + g * 8;
      vf[dt][0] = *(const bf16x8*)(Vp);
      vf[dt][1] = *(const bf16x8*)(Vp + 32);
    }

    // scale + causal mask (only last block touches the diagonal)
#pragma unroll
    for (int mt = 0; mt < 2; ++mt)
#pragma unroll
      for (int nt = 0; nt < 4; ++nt)
#pragma unroll
        for (int r = 0; r < 4; ++r) s[mt][nt][r] *= SCALE;
    if (it == nb - 1) {
#pragma unroll
      for (int mt = 0; mt < 2; ++mt)
#pragma unroll
        for (int nt = 0; nt < 4; ++nt)
#pragma unroll
          for (int r = 0; r < 4; ++r)
            if (nbase + nt * 16 + col > qbase + mt * 16 + g * 4 + r) s[mt][nt][r] = -1e30f;
    }

    // row max: 3 in-lane fmax + 4-step shfl over the 16 col lanes (both mt in parallel)
    float mv[2][4];
#pragma unroll
    for (int mt = 0; mt < 2; ++mt)
#pragma unroll
      for (int r = 0; r < 4; ++r)
        mv[mt][r] = fmaxf(fmaxf(s[mt][0][r], s[mt][1][r]), fmaxf(s[mt][2][r], s[mt][3][r]));
#pragma unroll
    for (int sh = 1; sh <= 8; sh <<= 1)
#pragma unroll
      for (int mt = 0; mt < 2; ++mt)
#pragma unroll
        for (int r = 0; r < 4; ++r) mv[mt][r] = fmaxf(mv[mt][r], __shfl_xor(mv[mt][r], sh, 64));

    // online softmax: exp in-place into s, rescale acc
#pragma unroll
    for (int mt = 0; mt < 2; ++mt)
#pragma unroll
      for (int r = 0; r < 4; ++r) {
        float mn = fmaxf(mrun[mt][r], mv[mt][r]);
        float rs = __expf(mrun[mt][r] - mn);
        mrun[mt][r] = mn;
        float ps = 0.f;
#pragma unroll
        for (int nt = 0; nt < 4; ++nt) {
          s[mt][nt][r] = __expf(s[mt][nt][r] - mn);
          ps += s[mt][nt][r];
        }
        lsum[mt][r] = lsum[mt][r] * rs + ps;
#pragma unroll
        for (int dt = 0; dt < 4; ++dt) acc[mt][dt][r] *= rs;
      }

    // P: D-layout -> A-layout via wave-private LDS
#pragma unroll
    for (int mt = 0; mt < 2; ++mt)
#pragma unroll
      for (int nt = 0; nt < 4; ++nt)
#pragma unroll
        for (int r = 0; r < 4; ++r)
          plds[w][mt][g * 4 + r][nt * 16 + col] = (__bf16)s[mt][nt][r];

    bf16x8 pa[2][2];
#pragma unroll
    for (int mt = 0; mt < 2; ++mt) {
      pa[mt][0] = *(const bf16x8*)&plds[w][mt][col][g * 8];
      pa[mt][1] = *(const bf16x8*)&plds[w][mt][col][32 + g * 8];
    }

    // PV: 16 MFMAs
#pragma unroll
    for (int mt = 0; mt < 2; ++mt)
#pragma unroll
      for (int dt = 0; dt < 4; ++dt) {
        f32x4 t = __builtin_amdgcn_mfma_f32_16x16x32_bf16(pa[mt][0], vf[dt][0], acc[mt][dt], 0, 0, 0);
        acc[mt][dt] = __builtin_amdgcn_mfma_f32_16x16x32_bf16(pa[mt][1], vf[dt][1], t, 0, 0, 0);
      }
  }

  // full row-sum for lsum (over 16 col lanes)
#pragma unroll
  for (int sh = 1; sh <= 8; sh <<= 1)
#pragma unroll
    for (int mt = 0; mt < 2; ++mt)
#pragma unroll
      for (int r = 0; r < 4; ++r) lsum[mt][r] += __shfl_xor(lsum[mt][r], sh, 64);

  // publish per-wave partial state
#pragma unroll
  for (int mt = 0; mt < 2; ++mt)
#pragma unroll
    for (int r = 0; r < 4; ++r) {
      int row = mt * 16 + g * 4 + r;
      accs[w][row][col]      = acc[mt][0][r];
      accs[w][row][col + 16] = acc[mt][1][r];
      accs[w][row][col + 32] = acc[mt][2][r];
      accs[w][row][col + 48] = acc[mt][3][r];
      if (col == 0) { mls[w][0][row] = mrun[mt][r]; mls[w][1][row] = lsum[mt][r]; }
    }
  __syncthreads();

  // combine the 4 KV-split partials; coalesced f32x4 output
#pragma unroll
  for (int pass = 0; pass < 2; ++pass) {
    int row = pass * 16 + (tid >> 4);
    int c4 = (tid & 15) * 4;
    float m0 = mls[0][0][row], m1 = mls[1][0][row];
    float m2 = mls[2][0][row], m3 = mls[3][0][row];
    float M = fmaxf(fmaxf(m0, m1), fmaxf(m2, m3));
    float s0 = __expf(m0 - M), s1 = __expf(m1 - M);
    float s2 = __expf(m2 - M), s3 = __expf(m3 - M);
    float L = s0 * mls[0][1][row] + s1 * mls[1][1][row]
            + s2 * mls[2][1][row] + s3 * mls[3][1][row];
    f32x4 a0 = *(const f32x4*)&accs[0][row][c4];
    f32x4 a1 = *(const f32x4*)&accs[1][row][c4];
    f32x4 a2 = *(const f32x4*)&accs[2][row][c4];
    f32x4 a3 = *(const f32x4*)&accs[3][row][c4];
    float inv = 1.f / L;
    f32x4 o;
#pragma unroll
    for (int j = 0; j < 4; ++j)
      o[j] = (s0 * a0[j] + s1 * a1[j] + s2 * a2[j] + s3 * a3[j]) * inv;
    *(f32x4*)(out + (size_t)(b * T_ + qbase + row) * DQ + c4) = o;
  }
}

extern "C" void kernel_launch(void* const* d_in, const int* in_sizes, int n_in,
                              void* d_out, int out_size, void* d_ws, size_t ws_size,
                              hipStream_t stream)
{
  const float* x  = (const float*)d_in[0];
  const float* Wq = (const float*)d_in[1];
  const float* Wk = (const float*)d_in[2];
  const float* Wv = (const float*)d_in[3];
  float* out = (float*)d_out;

  char* ws = (char*)d_ws;
  __bf16* Wt = (__bf16*)(ws);                                   // 384 KiB
  __bf16* Qb = (__bf16*)(ws + 0x80000);                         // 2 MiB
  __bf16* Kb = (__bf16*)(ws + 0x80000 + 0x200000);              // 2 MiB
  __bf16* Vt = (__bf16*)(ws + 0x80000 + 0x400000);              // 2 MiB

  kw_transpose<<<768, 256, 0, stream>>>(Wq, Wk, Wv, Wt);
  kproj<<<512, 256, 0, stream>>>(x, Wt, Qb, Kb, Vt);
  kattn<<<512, 256, 0, stream>>>(Qb, Kb, Vt, out);
}

// Round 4
// 54.074 us; speedup vs baseline: 2.2022x; 1.6287x over previous
//
#include <hip/hip_runtime.h>

typedef float f32x4 __attribute__((ext_vector_type(4)));
typedef __bf16 bf16x8 __attribute__((ext_vector_type(8)));
typedef __bf16 bf16x4 __attribute__((ext_vector_type(4)));

#define T_ 2048
#define DE 1024
#define DQ 64
#define SCALE 0.125f

#define GL16(gp, lp)                                                        \
  __builtin_amdgcn_global_load_lds(                                         \
      (const __attribute__((address_space(1))) void*)(gp),                  \
      (__attribute__((address_space(3))) void*)(lp), 16, 0, 0)

// ---------- kernel 0: pack W (3x [1024][64] f32) into fragment-major bf16 Wf.
// Wf[((ks*2+kh)*12 + t)*64 + lane][8]: element j = W[ks*64+kh*32+(lane>>4)*8+j][n],
// n = t*16 + (lane&15) globally, matrix = t/4.
__global__ __launch_bounds__(256) void kw_pack(
    const float* __restrict__ Wq, const float* __restrict__ Wk,
    const float* __restrict__ Wv, __bf16* __restrict__ Wf)
{
  int tid = blockIdx.x * 256 + threadIdx.x;   // 0..24575 = f*64 + lane
  int lane = tid & 63, f = tid >> 6;
  int t = f % 12, kh = (f / 12) & 1, ks = f / 24;
  const float* W = (t < 4) ? Wq : ((t < 8) ? Wk : Wv);
  int nl = ((t & 3) * 16 + (lane & 15));
  int k0 = ks * 64 + kh * 32 + (lane >> 4) * 8;
  bf16x8 v;
#pragma unroll
  for (int j = 0; j < 8; ++j) v[j] = (__bf16)W[(size_t)(k0 + j) * 64 + nl];
  *(bf16x8*)(Wf + (size_t)tid * 8) = v;
}

// ---------- kernel 1: QKV projection. Block = 32 m-rows. x staged fp32 via
// global_load_lds (double-buffered, source-swizzled); W frags reg-direct from L2.
__global__ __launch_bounds__(256) void kproj(
    const float* __restrict__ x, const __bf16* __restrict__ Wf,
    __bf16* __restrict__ Qb, __bf16* __restrict__ Kb, __bf16* __restrict__ Vt)
{
  __shared__ float xs[2][32 * 64];            // 16 KB total, swizzled storage
  const int tid = threadIdx.x;
  const int lane = tid & 63;
  const int w = tid >> 6;
  const int col = lane & 15, g = lane >> 4;
  const int mbase = blockIdx.x * 32;

  // per-lane constant source offsets for the 2 chunks this wave stages
  // chunk c covers rows c*4..c*4+3; lane l -> row c*4+(l>>4), 16B slot (l&15)
  size_t gsrc[2];
  int ldst[2];
#pragma unroll
  for (int cc = 0; cc < 2; ++cc) {
    int c = w * 2 + cc;
    int row = c * 4 + (lane >> 4);
    int kbyte = ((lane & 15) * 16) ^ ((row & 7) << 4);   // inverse-swizzled source
    gsrc[cc] = ((size_t)(mbase + row) << 12) + (size_t)kbyte;
    ldst[cc] = c * 1024;
  }

  f32x4 acc[2][3];
#pragma unroll
  for (int ms = 0; ms < 2; ++ms)
#pragma unroll
    for (int ii = 0; ii < 3; ++ii) acc[ms][ii] = (f32x4){0.f, 0.f, 0.f, 0.f};

  const char* xb = (const char*)x;
  // prologue: stage k-step 0 into buf 0
#pragma unroll
  for (int cc = 0; cc < 2; ++cc)
    GL16(xb + gsrc[cc], (char*)&xs[0][0] + ldst[cc]);
  __syncthreads();

  const int nt0 = w * 3;
  int buf = 0;
  for (int ks = 0; ks < 16; ++ks) {
    // stage next k-step into the other buffer (fire-and-forget)
    if (ks < 15) {
#pragma unroll
      for (int cc = 0; cc < 2; ++cc)
        GL16(xb + gsrc[cc] + (size_t)(ks + 1) * 256, (char*)&xs[buf ^ 1][0] + ldst[cc]);
    }

    // B fragments for this k-step: 3 n-tiles x 2 k-halves, 16B coalesced, L2-hot
    bf16x8 bfr[3][2];
#pragma unroll
    for (int ii = 0; ii < 3; ++ii)
#pragma unroll
      for (int kh = 0; kh < 2; ++kh)
        bfr[ii][kh] = *(const bf16x8*)(Wf +
            ((size_t)((ks * 2 + kh) * 12 + nt0 + ii) * 64 + lane) * 8);

    // A fragments from swizzled LDS + cvt, then MFMAs
#pragma unroll
    for (int kh = 0; kh < 2; ++kh) {
      bf16x8 afm[2];
#pragma unroll
      for (int ms = 0; ms < 2; ++ms) {
        int row = ms * 16 + col;
        int s = (row & 7) << 4;
        const char* base = (const char*)&xs[buf][0] + row * 256;
        int kb = kh * 128 + g * 32;
        f32x4 a0 = *(const f32x4*)(base + (kb ^ s));
        f32x4 a1 = *(const f32x4*)(base + ((kb + 16) ^ s));
        bf16x8 af;
#pragma unroll
        for (int j = 0; j < 4; ++j) { af[j] = (__bf16)a0[j]; af[4 + j] = (__bf16)a1[j]; }
        afm[ms] = af;
      }
#pragma unroll
      for (int ms = 0; ms < 2; ++ms)
#pragma unroll
        for (int ii = 0; ii < 3; ++ii)
          acc[ms][ii] = __builtin_amdgcn_mfma_f32_16x16x32_bf16(afm[ms], bfr[ii][kh],
                                                                acc[ms][ii], 0, 0, 0);
    }
    __syncthreads();          // drains this iter's global_load_lds + all ds_reads
    buf ^= 1;
  }

  // epilogue: D layout row = g*4+r (within 16-row tile), col = ti*16 + col
  const int b = mbase >> 11;
#pragma unroll
  for (int ms = 0; ms < 2; ++ms) {
    const int mrow = mbase + ms * 16 + g * 4;
    const int trow = (mbase & 2047) + ms * 16 + g * 4;
#pragma unroll
    for (int ii = 0; ii < 3; ++ii) {
      int ti = nt0 + ii;
      if (ti < 8) {
        __bf16* dst = (ti < 4) ? Qb : Kb;
        int c = (ti & 3) * 16 + col;
#pragma unroll
        for (int r = 0; r < 4; ++r)
          dst[(size_t)(mrow + r) * DQ + c] = (__bf16)acc[ms][ii][r];
      } else {
        int d = (ti - 8) * 16 + col;
        bf16x4 v;
#pragma unroll
        for (int r = 0; r < 4; ++r) v[r] = (__bf16)acc[ms][ii][r];
        *(bf16x4*)(Vt + ((size_t)(b * DQ + d)) * T_ + trow) = v;
      }
    }
  }
}

// ---------- kernel 2: causal flash attention. Block = 32 q-rows, 4 waves split KV (KVB=64).
__global__ __launch_bounds__(256) void kattn(
    const __bf16* __restrict__ Qb, const __bf16* __restrict__ Kb,
    const __bf16* __restrict__ Vt, float* __restrict__ out)
{
  __shared__ float accs[4][32][68];
  __shared__ float mls[4][2][32];
  __shared__ __bf16 plds[4][2][16][72];

  const int tid = threadIdx.x;
  const int lane = tid & 63;
  const int w = tid >> 6;
  const int col = lane & 15, g = lane >> 4;
  const int b = blockIdx.x & 7;
  const int jq = 63 - (blockIdx.x >> 3);
  const int qbase = jq * 32;

  bf16x8 qa[2][2];
#pragma unroll
  for (int mt = 0; mt < 2; ++mt) {
    const __bf16* Qp = Qb + (size_t)(b * T_ + qbase + mt * 16 + col) * DQ + g * 8;
    qa[mt][0] = *(const bf16x8*)(Qp);
    qa[mt][1] = *(const bf16x8*)(Qp + 32);
  }

  const __bf16* Kbb = Kb + (size_t)b * T_ * DQ;
  const __bf16* Vbb = Vt + (size_t)b * DQ * T_;

  f32x4 acc[2][4];
#pragma unroll
  for (int mt = 0; mt < 2; ++mt)
#pragma unroll
    for (int dt = 0; dt < 4; ++dt) acc[mt][dt] = (f32x4){0.f,0.f,0.f,0.f};
  float mrun[2][4], lsum[2][4];
#pragma unroll
  for (int mt = 0; mt < 2; ++mt)
#pragma unroll
    for (int r = 0; r < 4; ++r) { mrun[mt][r] = -1e30f; lsum[mt][r] = 0.f; }

  const int nb = (jq >> 1) + 1;
  for (int it = w; it < nb; it += 4) {
    const int nbase = it * 64;

    bf16x8 kf_[4][2];
#pragma unroll
    for (int nt = 0; nt < 4; ++nt) {
      const __bf16* Kp = Kbb + (size_t)(nbase + nt * 16 + col) * DQ + g * 8;
      kf_[nt][0] = *(const bf16x8*)(Kp);
      kf_[nt][1] = *(const bf16x8*)(Kp + 32);
    }

    f32x4 s[2][4];
#pragma unroll
    for (int mt = 0; mt < 2; ++mt)
#pragma unroll
      for (int nt = 0; nt < 4; ++nt) {
        f32x4 t = __builtin_amdgcn_mfma_f32_16x16x32_bf16(qa[mt][0], kf_[nt][0],
                                                          (f32x4){0.f,0.f,0.f,0.f}, 0, 0, 0);
        s[mt][nt] = __builtin_amdgcn_mfma_f32_16x16x32_bf16(qa[mt][1], kf_[nt][1], t, 0, 0, 0);
      }

    bf16x8 vf[4][2];
#pragma unroll
    for (int dt = 0; dt < 4; ++dt) {
      const __bf16* Vp = Vbb + (size_t)(dt * 16 + col) * T_ + nbase + g * 8;
      vf[dt][0] = *(const bf16x8*)(Vp);
      vf[dt][1] = *(const bf16x8*)(Vp + 32);
    }

#pragma unroll
    for (int mt = 0; mt < 2; ++mt)
#pragma unroll
      for (int nt = 0; nt < 4; ++nt)
#pragma unroll
        for (int r = 0; r < 4; ++r) s[mt][nt][r] *= SCALE;
    if (it == nb - 1) {
#pragma unroll
      for (int mt = 0; mt < 2; ++mt)
#pragma unroll
        for (int nt = 0; nt < 4; ++nt)
#pragma unroll
          for (int r = 0; r < 4; ++r)
            if (nbase + nt * 16 + col > qbase + mt * 16 + g * 4 + r) s[mt][nt][r] = -1e30f;
    }

    float mv[2][4];
#pragma unroll
    for (int mt = 0; mt < 2; ++mt)
#pragma unroll
      for (int r = 0; r < 4; ++r)
        mv[mt][r] = fmaxf(fmaxf(s[mt][0][r], s[mt][1][r]), fmaxf(s[mt][2][r], s[mt][3][r]));
#pragma unroll
    for (int sh = 1; sh <= 8; sh <<= 1)
#pragma unroll
      for (int mt = 0; mt < 2; ++mt)
#pragma unroll
        for (int r = 0; r < 4; ++r) mv[mt][r] = fmaxf(mv[mt][r], __shfl_xor(mv[mt][r], sh, 64));

#pragma unroll
    for (int mt = 0; mt < 2; ++mt)
#pragma unroll
      for (int r = 0; r < 4; ++r) {
        float mn = fmaxf(mrun[mt][r], mv[mt][r]);
        float rs = __expf(mrun[mt][r] - mn);
        mrun[mt][r] = mn;
        float ps = 0.f;
#pragma unroll
        for (int nt = 0; nt < 4; ++nt) {
          s[mt][nt][r] = __expf(s[mt][nt][r] - mn);
          ps += s[mt][nt][r];
        }
        lsum[mt][r] = lsum[mt][r] * rs + ps;
#pragma unroll
        for (int dt = 0; dt < 4; ++dt) acc[mt][dt][r] *= rs;
      }

#pragma unroll
    for (int mt = 0; mt < 2; ++mt)
#pragma unroll
      for (int nt = 0; nt < 4; ++nt)
#pragma unroll
        for (int r = 0; r < 4; ++r)
          plds[w][mt][g * 4 + r][nt * 16 + col] = (__bf16)s[mt][nt][r];

    bf16x8 pa[2][2];
#pragma unroll
    for (int mt = 0; mt < 2; ++mt) {
      pa[mt][0] = *(const bf16x8*)&plds[w][mt][col][g * 8];
      pa[mt][1] = *(const bf16x8*)&plds[w][mt][col][32 + g * 8];
    }

#pragma unroll
    for (int mt = 0; mt < 2; ++mt)
#pragma unroll
      for (int dt = 0; dt < 4; ++dt) {
        f32x4 t = __builtin_amdgcn_mfma_f32_16x16x32_bf16(pa[mt][0], vf[dt][0], acc[mt][dt], 0, 0, 0);
        acc[mt][dt] = __builtin_amdgcn_mfma_f32_16x16x32_bf16(pa[mt][1], vf[dt][1], t, 0, 0, 0);
      }
  }

#pragma unroll
  for (int sh = 1; sh <= 8; sh <<= 1)
#pragma unroll
    for (int mt = 0; mt < 2; ++mt)
#pragma unroll
      for (int r = 0; r < 4; ++r) lsum[mt][r] += __shfl_xor(lsum[mt][r], sh, 64);

#pragma unroll
  for (int mt = 0; mt < 2; ++mt)
#pragma unroll
    for (int r = 0; r < 4; ++r) {
      int row = mt * 16 + g * 4 + r;
      accs[w][row][col]      = acc[mt][0][r];
      accs[w][row][col + 16] = acc[mt][1][r];
      accs[w][row][col + 32] = acc[mt][2][r];
      accs[w][row][col + 48] = acc[mt][3][r];
      if (col == 0) { mls[w][0][row] = mrun[mt][r]; mls[w][1][row] = lsum[mt][r]; }
    }
  __syncthreads();

#pragma unroll
  for (int pass = 0; pass < 2; ++pass) {
    int row = pass * 16 + (tid >> 4);
    int c4 = (tid & 15) * 4;
    float m0 = mls[0][0][row], m1 = mls[1][0][row];
    float m2 = mls[2][0][row], m3 = mls[3][0][row];
    float M = fmaxf(fmaxf(m0, m1), fmaxf(m2, m3));
    float s0 = __expf(m0 - M), s1 = __expf(m1 - M);
    float s2 = __expf(m2 - M), s3 = __expf(m3 - M);
    float L = s0 * mls[0][1][row] + s1 * mls[1][1][row]
            + s2 * mls[2][1][row] + s3 * mls[3][1][row];
    f32x4 a0 = *(const f32x4*)&accs[0][row][c4];
    f32x4 a1 = *(const f32x4*)&accs[1][row][c4];
    f32x4 a2 = *(const f32x4*)&accs[2][row][c4];
    f32x4 a3 = *(const f32x4*)&accs[3][row][c4];
    float inv = 1.f / L;
    f32x4 o;
#pragma unroll
    for (int j = 0; j < 4; ++j)
      o[j] = (s0 * a0[j] + s1 * a1[j] + s2 * a2[j] + s3 * a3[j]) * inv;
    *(f32x4*)(out + (size_t)(b * T_ + qbase + row) * DQ + c4) = o;
  }
}

extern "C" void kernel_launch(void* const* d_in, const int* in_sizes, int n_in,
                              void* d_out, int out_size, void* d_ws, size_t ws_size,
                              hipStream_t stream)
{
  const float* x  = (const float*)d_in[0];
  const float* Wq = (const float*)d_in[1];
  const float* Wk = (const float*)d_in[2];
  const float* Wv = (const float*)d_in[3];
  float* out = (float*)d_out;

  char* ws = (char*)d_ws;
  __bf16* Wf = (__bf16*)(ws);                                   // 384 KiB
  __bf16* Qb = (__bf16*)(ws + 0x80000);                         // 2 MiB
  __bf16* Kb = (__bf16*)(ws + 0x80000 + 0x200000);              // 2 MiB
  __bf16* Vt = (__bf16*)(ws + 0x80000 + 0x400000);              // 2 MiB

  kw_pack<<<96, 256, 0, stream>>>(Wq, Wk, Wv, Wf);
  kproj<<<512, 256, 0, stream>>>(x, Wf, Qb, Kb, Vt);
  kattn<<<512, 256, 0, stream>>>(Qb, Kb, Vt, out);
}